// Round 4
// baseline (152.796 us; speedup 1.0000x reference)
//
#include <hip/hip_runtime.h>
#include <stdint.h>

#define NROWS 8192
#define KDIM  512                           // k elems (= bytes in fp8) per row
#define BM    256                           // 256x256 tiles
#define BK    64                            // k-bytes per stage
#define NKI   (KDIM / BK)                   // 8 K-iters
#define NT    (NROWS / BM)                  // 32 tiles per dim
#define NBLK  (NT * (NT + 1) / 2)           // 528 upper-tri tiles
#define NFULL 512                           // tiles 0..511 as full blocks
#define NGRID (NFULL + 2 * (NBLK - NFULL))  // 544: last 16 tiles as M-halves

typedef __attribute__((ext_vector_type(4)))  int   i32x4;
typedef __attribute__((ext_vector_type(8)))  int   i32x8;
typedef __attribute__((ext_vector_type(16))) float f32x16;

__device__ __forceinline__ void async_copy16(const unsigned char* g, unsigned char* l) {
  __builtin_amdgcn_global_load_lds(
      (const __attribute__((address_space(1))) unsigned int*)g,
      (__attribute__((address_space(3))) unsigned int*)l,
      16, 0, 0);
}

// Kernel 1: row-normalize fp32 -> fp8 e4m3 (RNE), one wave per row.
// PRE-SWIZZLE for BK=64 staging windows (R13-verified, absmax 0): within
// each 64B window, logical 16B chunk c stored at slot p = c ^ ((row>>1)&3).
// Per 16-lane ds_read_b128 phase: 2 row-parities x 4 slots x 4 words = 32
// banks, 2-way aliasing = free (m136). Halves inside chunks natural order.
__global__ __launch_bounds__(256) void prep_kernel(
    const float* __restrict__ src, unsigned char* __restrict__ dst,
    float* __restrict__ acc) {
  const int row  = blockIdx.x * 4 + (threadIdx.x >> 6);
  const int lane = threadIdx.x & 63;
  const float4 v0 = ((const float4*)src)[row * 128 + lane * 2];
  const float4 v1 = ((const float4*)src)[row * 128 + lane * 2 + 1];
  float ss = v0.x * v0.x + v0.y * v0.y + v0.z * v0.z + v0.w * v0.w
           + v1.x * v1.x + v1.y * v1.y + v1.z * v1.z + v1.w * v1.w;
  #pragma unroll
  for (int off = 32; off > 0; off >>= 1) ss += __shfl_down(ss, off);
  const float rn = 1.0f / sqrtf(__shfl(ss, 0));   // norms ~22.6, EPS never fires
  if (row == 0 && lane == 0) { acc[0] = 0.0f; ((unsigned int*)acc)[1] = 0u; }
  int pk0 = __builtin_amdgcn_cvt_pk_fp8_f32(v0.x * rn, v0.y * rn, 0, false);
  pk0     = __builtin_amdgcn_cvt_pk_fp8_f32(v0.z * rn, v0.w * rn, pk0, true);
  int pk1 = __builtin_amdgcn_cvt_pk_fp8_f32(v1.x * rn, v1.y * rn, 0, false);
  pk1     = __builtin_amdgcn_cvt_pk_fp8_f32(v1.z * rn, v1.w * rn, pk1, true);
  const int cg  = lane >> 1;                        // chunk in row (0..31)
  const int win = cg >> 2;                          // 64B window (0..7)
  const int p   = (cg & 3) ^ ((row >> 1) & 3);      // swizzle
  const int hf  = lane & 1;                         // natural half order
  uint2 o; o.x = (unsigned int)pk0; o.y = (unsigned int)pk1;
  ((uint2*)dst)[row * 64 + win * 8 + p * 2 + hf] = o;
}

__device__ __forceinline__ int tri_base(int b) {   // # tiles before row b
  return b * NT - (b * (b - 1)) / 2;
}

// Kernel 2: fp8 MX-MFMA GEMM (idn @ idn^T) fused with clamp, diag mask,
// reduction and finalize (completion counter).
// R14: (a) TAIL KILL -- 528 tiles = 2.06 rounds at 1 block/CU (190 VGPR ->
// 8 waves/CU, 2 blocks can never co-reside); the 16-tile third round idled
// 94% of the chip for a full block time. Now grid = 544: tiles 0..511 full
// (bid 0..511), tiles 512..527 split into M-halves of 128x256 (bid 512..543,
// dispatched last, ~t/2 each) -> makespan 3t -> ~2.5t. K is NOT split
// (relu(sum) != sum(relu)); M-split keeps full-K dot products so the clamp
// stays exact. Half-blocks re-load the same 128 A-rows for copy group i=1
// (stride 0, duplicate same-value LDS writes into the unread upper 8 KB) so
// the per-stage issue count stays 4 and vmcnt(4) stays compile-time.
// (b) T5 setprio(1) around the MFMA cluster.
// Barrier-uniformity note: the mi<MN predicate gates only register loads /
// MFMAs / epilogue adds, never any barrier -- all 512 threads hit every
// s_barrier and __syncthreads regardless of block shape.
__global__ __launch_bounds__(512, 2) void sim_reduce_kernel(
    const unsigned char* __restrict__ idn, float* __restrict__ acc,
    float* __restrict__ out) {
  // block -> (tile, half) mapping; halves dispatch last (ascending bids)
  const bool fullb = ((int)blockIdx.x < NFULL);
  const int  idx   = fullb ? (int)blockIdx.x
                           : NFULL + (((int)blockIdx.x - NFULL) >> 1);
  const int  half  = fullb ? 0 : (((int)blockIdx.x - NFULL) & 1);
  const int  MN    = fullb ? 4 : 2;          // mi-count (rows/wave = MN*32)

  // triangular decode (block-uniform scalar math, R1-proven)
  const float Af = 2.0f * NT + 1.0f;
  int bi = (int)((Af - sqrtf(Af * Af - 8.0f * (float)idx)) * 0.5f);
  while (bi > 0 && tri_base(bi) > idx) bi--;
  while (tri_base(bi + 1) <= idx) bi++;
  const int bj = bi + (idx - tri_base(bi));

  __shared__ __align__(16) unsigned char As[2][BM * BK];   // 2 x 16 KB
  __shared__ __align__(16) unsigned char Bs[2][BM * BK];   // 2 x 16 KB

  const int tid  = threadIdx.x;      // 0..511, 8 waves
  const int lane = tid & 63;
  const int w    = tid >> 6;
  const int mrows = fullb ? 128 : 64;          // rows per wave
  const int wrow  = (w >> 2) * mrows;          // local row base in staged region
  const int wcol  = (w & 3) * 64;
  const int r32  = lane & 31;        // row within 32-row MFMA tile
  const int h    = lane >> 5;        // k-half selector (k = h*32 + j)
  const int rx   = (r32 >> 1) & 3;   // chunk swizzle key

  f32x16 acc_f[4][2];
  #pragma unroll
  for (int i = 0; i < 4; i++)
    #pragma unroll
    for (int j = 0; j < 2; j++)
      acc_f[i][j] = (f32x16){0.f, 0.f, 0.f, 0.f, 0.f, 0.f, 0.f, 0.f,
                             0.f, 0.f, 0.f, 0.f, 0.f, 0.f, 0.f, 0.f};

  // Staging (R13-verified): per stage 1024 A + 1024 B chunks of 16B; copy i
  // (i=0,1), thread t covers chunk i*512+t: row = chunk>>2, slot = chunk&3.
  // LDS dest lane-linear (chunk*16); memory already holds swizzled slot
  // order so staging is a straight 64B-window copy, 4 lanes per window.
  // Half-blocks: A row base += half*128; i=1 group re-loads rows 0..127
  // (aStride=0) into the unread upper half of As.
  const unsigned char* gA =
      idn + (size_t)(bi * BM + half * 128 + (tid >> 2)) * KDIM + (tid & 3) * 16;
  const unsigned char* gB = idn + (size_t)(bj * BM + (tid >> 2)) * KDIM + (tid & 3) * 16;
  const size_t aStride = fullb ? 65536 : 0;    // 128 rows * 512 B, or re-load
  const int ldso = tid * 16;                   // + i*8192 per copy group

  // prologue: stage 0 <- k-window 0
  #pragma unroll
  for (int i = 0; i < 2; i++) async_copy16(gA + (size_t)i * aStride, &As[0][ldso + i * 8192]);
  #pragma unroll
  for (int i = 0; i < 2; i++) async_copy16(gB + (size_t)i * 65536, &Bs[0][ldso + i * 8192]);

  // frag slots: logical chunks c0=2h, c0+1 at swizzled positions (hoisted)
  const int p0 = ((2 * h)     ^ rx) * 16;
  const int p1 = ((2 * h + 1) ^ rx) * 16;

  #pragma unroll
  for (int t = 0; t < NKI; ++t) {
    const int cs = t & 1;
    if (t + 1 < NKI) {
      const int ns = cs ^ 1;
      const int ko = (t + 1) * BK;
      #pragma unroll
      for (int i = 0; i < 2; i++)
        async_copy16(gA + ko + (size_t)i * aStride, &As[ns][ldso + i * 8192]);
      #pragma unroll
      for (int i = 0; i < 2; i++)
        async_copy16(gB + ko + (size_t)i * 65536, &Bs[ns][ldso + i * 8192]);
      asm volatile("s_waitcnt vmcnt(4)" ::: "memory");  // stage t landed; t+1 in flight
    } else {
      asm volatile("s_waitcnt vmcnt(0)" ::: "memory");
    }
    asm volatile("s_barrier" ::: "memory");   // all waves' stage-t fills visible

    // One K=64 slice per stage: MN A-frags + 2 B-frags, each 2x ds_read_b128.
    i32x8 af[4], bf[2];
    #pragma unroll
    for (int ni = 0; ni < 2; ni++) {
      const unsigned char* bb = &Bs[cs][(wcol + ni * 32 + r32) * BK];
      const i32x4 blo = *(const i32x4*)(bb + p0);
      const i32x4 bhi = *(const i32x4*)(bb + p1);
      bf[ni] = __builtin_shufflevector(blo, bhi, 0, 1, 2, 3, 4, 5, 6, 7);
    }
    #pragma unroll
    for (int mi = 0; mi < 4; mi++)
      if (mi < MN) {
        const unsigned char* ab = &As[cs][(wrow + mi * 32 + r32) * BK];
        const i32x4 alo = *(const i32x4*)(ab + p0);
        const i32x4 ahi = *(const i32x4*)(ab + p1);
        af[mi] = __builtin_shufflevector(alo, ahi, 0, 1, 2, 3, 4, 5, 6, 7);
      }
    __builtin_amdgcn_s_setprio(1);            // T5: favor MFMA-issuing wave
    #pragma unroll
    for (int mi = 0; mi < 4; mi++)
      if (mi < MN)
        #pragma unroll
        for (int ni = 0; ni < 2; ni++)
          acc_f[mi][ni] = __builtin_amdgcn_mfma_scale_f32_32x32x64_f8f6f4(
              af[mi], bf[ni], acc_f[mi][ni],
              0, 0,                       // A fmt = fp8 e4m3, B fmt = fp8 e4m3
              0, 0x7F7F7F7Fu,             // A scale: E8M0 127 -> 1.0
              0, 0x7F7F7F7Fu);            // B scale: E8M0 127 -> 1.0
    __builtin_amdgcn_s_setprio(0);

    asm volatile("s_barrier" ::: "memory");   // compute(t) done before t+1 refill
  }

  // Epilogue: clamp at zero, mask diagonal, reduce.
  // C/D layout for 32x32 shapes (m74/m101; dtype-independent m121-m128):
  // col = lane&31, row = (reg&3) + 8*(reg>>2) + 4*(lane>>5). R12/R13-verified.
  float local = 0.f;
  const bool diag = (bi == bj);
  #pragma unroll
  for (int mi = 0; mi < 4; mi++)
    if (mi < MN)
      #pragma unroll
      for (int ni = 0; ni < 2; ni++)
        #pragma unroll
        for (int rg = 0; rg < 16; rg++) {
          const int ri = half * 128 + wrow + mi * 32 + (rg & 3) + 8 * (rg >> 2) + 4 * h;
          const int ci = wcol + ni * 32 + r32;
          float v = fmaxf(acc_f[mi][ni][rg], 0.f);
          if (diag && ri == ci) v = 0.f;
          local += v;
        }

  #pragma unroll
  for (int off = 32; off > 0; off >>= 1) local += __shfl_down(local, off);
  __syncthreads();                   // staging dead; reuse As for reduce
  float* red = (float*)As;
  if (lane == 0) red[w] = local;
  __syncthreads();
  if (tid == 0) {
    float s = red[0] + red[1] + red[2] + red[3]
            + red[4] + red[5] + red[6] + red[7];
    if (!diag) s *= 2.f;             // strictly-upper tiles cover both triangles
    atomicAdd(acc, s);
    // fused finalize: last-arriving block scales and writes both outputs.
    __threadfence();                               // acc-add visible before count
    unsigned int done = atomicAdd((unsigned int*)(acc + 1), 1u);
    if (done == NGRID - 1) {
      float total = atomicAdd(acc, 0.0f);          // device-scope RMW read
      const float m = total * (1.0f / ((float)NROWS * (float)NROWS));
      out[0] = m;
      out[1] = m;
    }
  }
}

extern "C" void kernel_launch(void* const* d_in, const int* in_sizes, int n_in,
                              void* d_out, int out_size, void* d_ws, size_t ws_size,
                              hipStream_t stream) {
  const float* id = (const float*)d_in[0];
  float* out = (float*)d_out;
  unsigned char* idn = (unsigned char*)d_ws;                       // 4 MB fp8
  float* acc = (float*)((char*)d_ws + (size_t)NROWS * KDIM);       // [0]=sum, [1]=counter

  prep_kernel<<<NROWS / 4, 256, 0, stream>>>(id, idn, acc);
  sim_reduce_kernel<<<NGRID, 512, 0, stream>>>(idn, acc, out);
}

// Round 5
// 97.756 us; speedup vs baseline: 1.5630x; 1.5630x over previous
//
#include <hip/hip_runtime.h>
#include <stdint.h>

#define NROWS 8192
#define KDIM  512                           // k elems (= bytes in fp8) per row
#define BM    256                           // full tile edge
#define BK    64                            // k-bytes per stage
#define NKI   (KDIM / BK)                   // 8 K-iters
#define NT    (NROWS / BM)                  // 32 tiles per dim
#define NBLK  (NT * (NT + 1) / 2)           // 528 upper-tri tiles
#define NFULL 512                           // tiles 0..511 as full blocks
#define NTAIL (NBLK - NFULL)                // 16 tiles as 2x M-halves each
#define NTOTAL (NFULL + 2 * NTAIL)          // 544 completion-counter target

typedef __attribute__((ext_vector_type(4)))  int   i32x4;
typedef __attribute__((ext_vector_type(8)))  int   i32x8;
typedef __attribute__((ext_vector_type(16))) float f32x16;

__device__ __forceinline__ void async_copy16(const unsigned char* g, unsigned char* l) {
  __builtin_amdgcn_global_load_lds(
      (const __attribute__((address_space(1))) unsigned int*)g,
      (__attribute__((address_space(3))) unsigned int*)l,
      16, 0, 0);
}

// Kernel 1: row-normalize fp32 -> fp8 e4m3 (RNE), one wave per row.
// PRE-SWIZZLE for BK=64 staging windows (R13-verified, absmax 0): within
// each 64B window, logical 16B chunk c stored at slot p = c ^ ((row>>1)&3).
// Per 16-lane ds_read_b128 phase: 2 row-parities x 4 slots x 4 words = 32
// banks, 2-way aliasing = free (m136). Halves inside chunks natural order.
__global__ __launch_bounds__(256) void prep_kernel(
    const float* __restrict__ src, unsigned char* __restrict__ dst,
    float* __restrict__ acc) {
  const int row  = blockIdx.x * 4 + (threadIdx.x >> 6);
  const int lane = threadIdx.x & 63;
  const float4 v0 = ((const float4*)src)[row * 128 + lane * 2];
  const float4 v1 = ((const float4*)src)[row * 128 + lane * 2 + 1];
  float ss = v0.x * v0.x + v0.y * v0.y + v0.z * v0.z + v0.w * v0.w
           + v1.x * v1.x + v1.y * v1.y + v1.z * v1.z + v1.w * v1.w;
  #pragma unroll
  for (int off = 32; off > 0; off >>= 1) ss += __shfl_down(ss, off);
  const float rn = 1.0f / sqrtf(__shfl(ss, 0));   // norms ~22.6, EPS never fires
  if (row == 0 && lane == 0) { acc[0] = 0.0f; ((unsigned int*)acc)[1] = 0u; }
  int pk0 = __builtin_amdgcn_cvt_pk_fp8_f32(v0.x * rn, v0.y * rn, 0, false);
  pk0     = __builtin_amdgcn_cvt_pk_fp8_f32(v0.z * rn, v0.w * rn, pk0, true);
  int pk1 = __builtin_amdgcn_cvt_pk_fp8_f32(v1.x * rn, v1.y * rn, 0, false);
  pk1     = __builtin_amdgcn_cvt_pk_fp8_f32(v1.z * rn, v1.w * rn, pk1, true);
  const int cg  = lane >> 1;                        // chunk in row (0..31)
  const int win = cg >> 2;                          // 64B window (0..7)
  const int p   = (cg & 3) ^ ((row >> 1) & 3);      // swizzle
  const int hf  = lane & 1;                         // natural half order
  uint2 o; o.x = (unsigned int)pk0; o.y = (unsigned int)pk1;
  ((uint2*)dst)[row * 64 + win * 8 + p * 2 + hf] = o;
}

__device__ __forceinline__ int tri_base(int b) {   // # tiles before row b
  return b * NT - (b * (b - 1)) / 2;
}

// Kernel 2: fp8 MX-MFMA GEMM (idn @ idn^T) fused with clamp, diag mask,
// reduction, finalize (completion counter, target NTOTAL across BOTH grids).
// R15: R14's runtime `if (mi < MN)` predication demoted acc_f to SCRATCH
// (VGPR 128 = accs don't fit; WRITE_SIZE 142 MB == 544*512*512B spill,
// exact match) -- 2.4 TB of scratch traffic made sim 95us. Fix: MN is now a
// TEMPLATE parameter; two stream-ordered launches:
//   sim<4> x 512 blocks: full 256x256 tiles, exactly 2 rounds at 1 blk/CU
//   sim<2> x 32 blocks:  last 16 tiles as 128x256 M-halves, ~t/2 round
// Makespan ~2.5t vs R13's 3.06t (16-block third round idled 94% of chip).
// K is NOT split (relu(sum) != sum(relu)); M-split keeps full-K dots exact.
// All loop bounds / LDS sizes / vmcnt literals compile-time; zero runtime
// control flow in the hot loop. setprio dropped this round (R14 bundled it
// with the spill -- no clean signal; re-test later in isolation).
template <int MN>                      // 4 = full 256 rows, 2 = half 128 rows
__global__ __launch_bounds__(512, 2) void sim_reduce_kernel(
    const unsigned char* __restrict__ idn, float* __restrict__ acc,
    float* __restrict__ out) {
  constexpr int AROWS = MN * 64;       // staged A rows per block: 256 / 128
  constexpr int ACOP  = MN / 2;        // A copies per thread per stage: 2 / 1

  const int idx  = (MN == 4) ? (int)blockIdx.x : NFULL + ((int)blockIdx.x >> 1);
  const int half = (MN == 4) ? 0 : ((int)blockIdx.x & 1);

  // triangular decode (block-uniform scalar math, R1-proven)
  const float Af = 2.0f * NT + 1.0f;
  int bi = (int)((Af - sqrtf(Af * Af - 8.0f * (float)idx)) * 0.5f);
  while (bi > 0 && tri_base(bi) > idx) bi--;
  while (tri_base(bi + 1) <= idx) bi++;
  const int bj = bi + (idx - tri_base(bi));

  __shared__ __align__(16) unsigned char As[2][AROWS * BK];  // 16 / 8 KB each
  __shared__ __align__(16) unsigned char Bs[2][BM * BK];     // 16 KB each

  const int tid  = threadIdx.x;      // 0..511, 8 waves
  const int lane = tid & 63;
  const int w    = tid >> 6;
  const int wrow = (w >> 2) * (MN * 32);   // wave row base in staged region
  const int wcol = (w & 3) * 64;
  const int r32  = lane & 31;        // row within 32-row MFMA tile
  const int h    = lane >> 5;        // k-half selector (k = h*32 + j)
  const int rx   = (r32 >> 1) & 3;   // chunk swizzle key

  f32x16 acc_f[MN][2];
  #pragma unroll
  for (int i = 0; i < MN; i++)
    #pragma unroll
    for (int j = 0; j < 2; j++)
      acc_f[i][j] = (f32x16){0.f, 0.f, 0.f, 0.f, 0.f, 0.f, 0.f, 0.f,
                             0.f, 0.f, 0.f, 0.f, 0.f, 0.f, 0.f, 0.f};

  // Staging (R13-verified): per stage AROWS*4 A-chunks + 1024 B-chunks of
  // 16B; copy i, thread t covers chunk i*512+t: row = chunk>>2, slot =
  // chunk&3. LDS dest lane-linear (chunk*16, global_load_lds constraint);
  // memory already holds swizzled slot order so staging is a straight
  // 64B-window copy, 4 lanes per window.
  const unsigned char* gA =
      idn + (size_t)(bi * BM + half * 128 + (tid >> 2)) * KDIM + (tid & 3) * 16;
  const unsigned char* gB = idn + (size_t)(bj * BM + (tid >> 2)) * KDIM + (tid & 3) * 16;
  const int ldso = tid * 16;         // + i*8192 per copy group

  // prologue: stage 0 <- k-window 0
  #pragma unroll
  for (int i = 0; i < ACOP; i++) async_copy16(gA + (size_t)i * 65536, &As[0][ldso + i * 8192]);
  #pragma unroll
  for (int i = 0; i < 2; i++)    async_copy16(gB + (size_t)i * 65536, &Bs[0][ldso + i * 8192]);

  // frag slots: logical chunks c0=2h, c0+1 at swizzled positions (hoisted)
  const int p0 = ((2 * h)     ^ rx) * 16;
  const int p1 = ((2 * h + 1) ^ rx) * 16;

  #pragma unroll
  for (int t = 0; t < NKI; ++t) {
    const int cs = t & 1;
    if (t + 1 < NKI) {
      const int ns = cs ^ 1;
      const int ko = (t + 1) * BK;
      #pragma unroll
      for (int i = 0; i < ACOP; i++)
        async_copy16(gA + ko + (size_t)i * 65536, &As[ns][ldso + i * 8192]);
      #pragma unroll
      for (int i = 0; i < 2; i++)
        async_copy16(gB + ko + (size_t)i * 65536, &Bs[ns][ldso + i * 8192]);
      // stage t's (ACOP+2) copies landed; stage t+1's (ACOP+2) stay in flight
      if constexpr (MN == 4) asm volatile("s_waitcnt vmcnt(4)" ::: "memory");
      else                   asm volatile("s_waitcnt vmcnt(3)" ::: "memory");
    } else {
      asm volatile("s_waitcnt vmcnt(0)" ::: "memory");
    }
    asm volatile("s_barrier" ::: "memory");   // all waves' stage-t fills visible

    // One K=64 slice per stage: MN A-frags + 2 B-frags, each 2x ds_read_b128.
    i32x8 af[MN], bf[2];
    #pragma unroll
    for (int ni = 0; ni < 2; ni++) {
      const unsigned char* bb = &Bs[cs][(wcol + ni * 32 + r32) * BK];
      const i32x4 blo = *(const i32x4*)(bb + p0);
      const i32x4 bhi = *(const i32x4*)(bb + p1);
      bf[ni] = __builtin_shufflevector(blo, bhi, 0, 1, 2, 3, 4, 5, 6, 7);
    }
    #pragma unroll
    for (int mi = 0; mi < MN; mi++) {
      const unsigned char* ab = &As[cs][(wrow + mi * 32 + r32) * BK];
      const i32x4 alo = *(const i32x4*)(ab + p0);
      const i32x4 ahi = *(const i32x4*)(ab + p1);
      af[mi] = __builtin_shufflevector(alo, ahi, 0, 1, 2, 3, 4, 5, 6, 7);
    }
    #pragma unroll
    for (int mi = 0; mi < MN; mi++)
      #pragma unroll
      for (int ni = 0; ni < 2; ni++)
        acc_f[mi][ni] = __builtin_amdgcn_mfma_scale_f32_32x32x64_f8f6f4(
            af[mi], bf[ni], acc_f[mi][ni],
            0, 0,                       // A fmt = fp8 e4m3, B fmt = fp8 e4m3
            0, 0x7F7F7F7Fu,             // A scale: E8M0 127 -> 1.0
            0, 0x7F7F7F7Fu);            // B scale: E8M0 127 -> 1.0

    asm volatile("s_barrier" ::: "memory");   // compute(t) done before t+1 refill
  }

  // Epilogue: clamp at zero, mask diagonal, reduce.
  // C/D layout for 32x32 shapes (m74/m101; dtype-independent m121-m128):
  // col = lane&31, row = (reg&3) + 8*(reg>>2) + 4*(lane>>5). R12/R13-verified.
  float local = 0.f;
  const bool diag = (bi == bj);
  #pragma unroll
  for (int mi = 0; mi < MN; mi++)
    #pragma unroll
    for (int ni = 0; ni < 2; ni++)
      #pragma unroll
      for (int rg = 0; rg < 16; rg++) {
        const int ri = half * 128 + wrow + mi * 32 + (rg & 3) + 8 * (rg >> 2) + 4 * h;
        const int ci = wcol + ni * 32 + r32;
        float v = fmaxf(acc_f[mi][ni][rg], 0.f);
        if (diag && ri == ci) v = 0.f;
        local += v;
      }

  #pragma unroll
  for (int off = 32; off > 0; off >>= 1) local += __shfl_down(local, off);
  __syncthreads();                   // staging dead; reuse Bs for reduce
  float* red = (float*)Bs;
  if (lane == 0) red[w] = local;
  __syncthreads();
  if (tid == 0) {
    float s = red[0] + red[1] + red[2] + red[3]
            + red[4] + red[5] + red[6] + red[7];
    if (!diag) s *= 2.f;             // strictly-upper tiles cover both triangles
    atomicAdd(acc, s);
    // fused finalize: last-arriving block (across both grids) writes outputs.
    __threadfence();                               // acc-add visible before count
    unsigned int done = atomicAdd((unsigned int*)(acc + 1), 1u);
    if (done == NTOTAL - 1) {
      float total = atomicAdd(acc, 0.0f);          // device-scope RMW read
      const float m = total * (1.0f / ((float)NROWS * (float)NROWS));
      out[0] = m;
      out[1] = m;
    }
  }
}

extern "C" void kernel_launch(void* const* d_in, const int* in_sizes, int n_in,
                              void* d_out, int out_size, void* d_ws, size_t ws_size,
                              hipStream_t stream) {
  const float* id = (const float*)d_in[0];
  float* out = (float*)d_out;
  unsigned char* idn = (unsigned char*)d_ws;                       // 4 MB fp8
  float* acc = (float*)((char*)d_ws + (size_t)NROWS * KDIM);       // [0]=sum, [1]=counter

  prep_kernel<<<NROWS / 4, 256, 0, stream>>>(id, idn, acc);
  sim_reduce_kernel<4><<<NFULL, 512, 0, stream>>>(idn, acc, out);      // 2 full rounds
  sim_reduce_kernel<2><<<2 * NTAIL, 512, 0, stream>>>(idn, acc, out);  // ~t/2 tail
}